// Round 1
// baseline (101.984 us; speedup 1.0000x reference)
//
#include <hip/hip_runtime.h>
#include <hip/hip_bf16.h>
#include <math.h>

#define EPSLN 1e-5f

typedef __attribute__((ext_vector_type(8))) short short8;
typedef __attribute__((ext_vector_type(4))) float f32x4;
typedef __attribute__((ext_vector_type(4))) unsigned short u16x4;

__device__ inline unsigned short f2bf(float f){
  unsigned int u = __float_as_uint(f);
  u += 0x7fffu + ((u >> 16) & 1u);
  return (unsigned short)(u >> 16);
}

__device__ inline float wred(float v){
  #pragma unroll
  for(int o = 32; o > 0; o >>= 1) v += __shfl_down(v, o, 64);
  return v;
}

// ---------------------------------------------------------------------------
// K1: per-batch column sum of LN1(x).  256 blocks (4 batches x 64), 16 rows/blk
// ---------------------------------------------------------------------------
__global__ __launch_bounds__(256) void ln1_colsum(
    const float* __restrict__ x, const float* __restrict__ w,
    const float* __restrict__ bb, float* __restrict__ colsum)
{
  const int tid = threadIdx.x, lane = tid & 63, wv = tid >> 6;
  const int b = blockIdx.x >> 6, rblk = blockIdx.x & 63;
  __shared__ float red[8];
  float2 w2 = ((const float2*)w)[tid];
  float2 b2 = ((const float2*)bb)[tid];
  float a0 = 0.f, a1 = 0.f;
  for(int i = 0; i < 16; i++){
    int row = (b << 10) + (rblk << 4) + i;
    float2 xv = ((const float2*)x)[(size_t)row * 256 + tid];
    float s = xv.x + xv.y, q = xv.x * xv.x + xv.y * xv.y;
    s = wred(s); q = wred(q);
    if(lane == 0){ red[wv] = s; red[4 + wv] = q; }
    __syncthreads();
    if(tid == 0){
      float su = red[0] + red[1] + red[2] + red[3];
      float sq = red[4] + red[5] + red[6] + red[7];
      float mu = su * (1.f / 512.f);
      float var = sq * (1.f / 512.f) - mu * mu;
      red[0] = mu; red[1] = rsqrtf(var + EPSLN);
    }
    __syncthreads();
    float mu = red[0], rs = red[1];
    a0 += (xv.x - mu) * rs * w2.x + b2.x;
    a1 += (xv.y - mu) * rs * w2.y + b2.y;
    __syncthreads();
  }
  atomicAdd(&colsum[(b << 9) + tid * 2    ], a0);
  atomicAdd(&colsum[(b << 9) + tid * 2 + 1], a1);
}

// ---------------------------------------------------------------------------
// K2: out[b*512+n] = scale * dot(vec[b], W[n]) + bias[n]    (wave per output)
// ---------------------------------------------------------------------------
__global__ __launch_bounds__(256) void matvec512(
    const float* __restrict__ vec, const float* __restrict__ Wm,
    const float* __restrict__ bias, float* __restrict__ outv, float scale)
{
  int gw = blockIdx.x * 4 + (threadIdx.x >> 6);
  int lane = threadIdx.x & 63;
  int b = gw >> 9, n = gw & 511;
  const f32x4* vr = (const f32x4*)(vec + ((size_t)b << 9));
  const f32x4* wr = (const f32x4*)(Wm + ((size_t)n << 9));
  f32x4 v1 = vr[lane * 2], v2 = vr[lane * 2 + 1];
  f32x4 w1 = wr[lane * 2], w2 = wr[lane * 2 + 1];
  float s = 0.f;
  #pragma unroll
  for(int i = 0; i < 4; i++) s += v1[i] * w1[i] + v2[i] * w2[i];
  s = wred(s);
  if(lane == 0) outv[gw] = s * scale + bias[n];
}

// ---------------------------------------------------------------------------
// K3: x2 = x + attn_row (broadcast over seq); xl2 = LN2(x2) as bf16
// ---------------------------------------------------------------------------
__global__ __launch_bounds__(256) void add_ln2(
    const float* __restrict__ x, const float* __restrict__ arow,
    const float* __restrict__ w, const float* __restrict__ bb,
    float* __restrict__ x2, unsigned short* __restrict__ xl2)
{
  const int tid = threadIdx.x, lane = tid & 63, wv = tid >> 6;
  const int row = blockIdx.x, b = row >> 10;
  __shared__ float red[8];
  float2 xv = ((const float2*)x)[(size_t)row * 256 + tid];
  float2 av = ((const float2*)arow)[(b << 8) + tid];
  float2 t; t.x = xv.x + av.x; t.y = xv.y + av.y;
  ((float2*)x2)[(size_t)row * 256 + tid] = t;
  float s = t.x + t.y, q = t.x * t.x + t.y * t.y;
  s = wred(s); q = wred(q);
  if(lane == 0){ red[wv] = s; red[4 + wv] = q; }
  __syncthreads();
  if(tid == 0){
    float su = red[0] + red[1] + red[2] + red[3];
    float sq = red[4] + red[5] + red[6] + red[7];
    float mu = su * (1.f / 512.f);
    float var = sq * (1.f / 512.f) - mu * mu;
    red[0] = mu; red[1] = rsqrtf(var + EPSLN);
  }
  __syncthreads();
  float mu = red[0], rs = red[1];
  float2 w2 = ((const float2*)w)[tid], b2 = ((const float2*)bb)[tid];
  ushort2 o;
  o.x = f2bf((t.x - mu) * rs * w2.x + b2.x);
  o.y = f2bf((t.y - mu) * rs * w2.y + b2.y);
  ((ushort2*)xl2)[(size_t)row * 256 + tid] = o;
}

// ---------------------------------------------------------------------------
// K4: f32 -> bf16 conversion (4 elems/thread, n divisible by 1024)
// ---------------------------------------------------------------------------
__global__ __launch_bounds__(256) void cvt_bf16(
    const float* __restrict__ in, unsigned short* __restrict__ o, int n)
{
  int i = (blockIdx.x * 256 + threadIdx.x) * 4;
  if(i >= n) return;
  f32x4 v = *(const f32x4*)(in + i);
  u16x4 r;
  #pragma unroll
  for(int j = 0; j < 4; j++) r[j] = f2bf(v[j]);
  *(u16x4*)(o + i) = r;
}

// ---------------------------------------------------------------------------
// K5: bf16 MFMA GEMM  out[m,n] = sum_k A[m,k]*W[n,k] (+bias, +epilogue)
// BM=128, BK=32, 4 waves in 2x2, each wave 64 x (BN/2).
// EPI==0: gelu -> bf16 out ; EPI==1: +res -> f32 out
// ---------------------------------------------------------------------------
__device__ inline void gld_lds16(const void* g, void* l){
  __builtin_amdgcn_global_load_lds(
      (const __attribute__((address_space(1))) void*)g,
      (__attribute__((address_space(3))) void*)l, 16, 0, 0);
}

template<int BN, int EPI>
__global__ __launch_bounds__(256) void gemm_bt(
    const unsigned short* __restrict__ A, const unsigned short* __restrict__ W,
    const float* __restrict__ bias, const float* __restrict__ res,
    void* __restrict__ outp, int M, int N, int K)
{
  constexpr int BM = 128, BK = 32, NI = BN / 32;
  __shared__ __align__(16) unsigned short sA[BM * BK];
  __shared__ __align__(16) unsigned short sB[BN * BK];
  const int tid = threadIdx.x, lane = tid & 63, wv = tid >> 6;
  const int wm = wv >> 1, wn = wv & 1;
  const int m0 = blockIdx.x * BM, n0 = blockIdx.y * BN;

  f32x4 acc[4][NI];
  #pragma unroll
  for(int i = 0; i < 4; i++)
    #pragma unroll
    for(int j = 0; j < NI; j++) acc[i][j] = (f32x4)(0.f);

  const int rowA  = tid >> 2;        // (tid*16)/64
  const int colbA = (tid & 3) * 16;  // byte within 64B row

  for(int k0 = 0; k0 < K; k0 += BK){
    #pragma unroll
    for(int p = 0; p < BM / 64; p++){
      const char* g = (const char*)(A + (size_t)(m0 + rowA + p * 64) * K + k0) + colbA;
      gld_lds16(g, (char*)sA + p * 4096 + wv * 1024);
    }
    #pragma unroll
    for(int p = 0; p < BN / 64; p++){
      const char* g = (const char*)(W + (size_t)(n0 + rowA + p * 64) * K + k0) + colbA;
      gld_lds16(g, (char*)sB + p * 4096 + wv * 1024);
    }
    __syncthreads();

    short8 af[4], bf[NI];
    const int kof = (lane >> 4) * 8;
    #pragma unroll
    for(int mi = 0; mi < 4; mi++)
      af[mi] = *(const short8*)(sA + (wm * 64 + mi * 16 + (lane & 15)) * BK + kof);
    #pragma unroll
    for(int ni = 0; ni < NI; ni++)
      bf[ni] = *(const short8*)(sB + (wn * (BN / 2) + ni * 16 + (lane & 15)) * BK + kof);

    #pragma unroll
    for(int mi = 0; mi < 4; mi++)
      #pragma unroll
      for(int ni = 0; ni < NI; ni++)
        acc[mi][ni] = __builtin_amdgcn_mfma_f32_16x16x32_bf16(af[mi], bf[ni], acc[mi][ni], 0, 0, 0);
    __syncthreads();
  }

  const int r0 = m0 + wm * 64 + (lane >> 4) * 4;
  const int c0 = n0 + wn * (BN / 2) + (lane & 15);
  #pragma unroll
  for(int mi = 0; mi < 4; mi++)
    #pragma unroll
    for(int ni = 0; ni < NI; ni++){
      int cc = c0 + ni * 16;
      float bi = bias[cc];
      #pragma unroll
      for(int j = 0; j < 4; j++){
        int rr = r0 + mi * 16 + j;
        float v = acc[mi][ni][j] + bi;
        if constexpr(EPI == 0){
          float gl = 0.5f * v * (1.0f + erff(v * 0.70710678118f));
          ((unsigned short*)outp)[(size_t)rr * N + cc] = f2bf(gl);
        } else {
          v += res[(size_t)rr * N + cc];
          ((float*)outp)[(size_t)rr * N + cc] = v;
        }
      }
    }
}

// ---------------------------------------------------------------------------
extern "C" void kernel_launch(void* const* d_in, const int* in_sizes, int n_in,
                              void* d_out, int out_size, void* d_ws, size_t ws_size,
                              hipStream_t stream)
{
  (void)in_sizes; (void)n_in; (void)out_size; (void)ws_size;
  const float* x    = (const float*)d_in[0];
  const float* ln1w = (const float*)d_in[1];
  const float* ln1b = (const float*)d_in[2];
  const float* qkvw = (const float*)d_in[3];
  const float* qkvb = (const float*)d_in[4];
  const float* outw = (const float*)d_in[5];
  const float* outb = (const float*)d_in[6];
  const float* ln2w = (const float*)d_in[7];
  const float* ln2b = (const float*)d_in[8];
  const float* fc1w = (const float*)d_in[9];
  const float* fc1b = (const float*)d_in[10];
  const float* fc2w = (const float*)d_in[11];
  const float* fc2b = (const float*)d_in[12];

  char* ws = (char*)d_ws;
  float*          colsum = (float*)ws;                      // 8 KB
  float*          vmean  = (float*)(ws + 8192);             // 8 KB
  float*          arow   = (float*)(ws + 16384);            // 8 KB
  float*          x2     = (float*)(ws + 32768);            // 8 MB
  unsigned short* xl2    = (unsigned short*)(ws + 32768 + 8388608);            // 4 MB
  unsigned short* w1b    = (unsigned short*)(ws + 32768 + 8388608 + 4194304); // 2 MB
  unsigned short* w2b    = (unsigned short*)(ws + 32768 + 8388608 + 4194304 + 2097152); // 2 MB
  unsigned short* hact   = (unsigned short*)(ws + 32768 + 8388608 + 4194304 + 2097152 + 2097152); // 16 MB

  hipMemsetAsync(colsum, 0, 2048 * 4, stream);
  ln1_colsum<<<256, 256, 0, stream>>>(x, ln1w, ln1b, colsum);
  // v_mean = (colsum/S) @ Wv^T + bv   (Wv = qkv_w rows [1024,1536))
  matvec512<<<512, 256, 0, stream>>>(colsum, qkvw + 2 * 512 * 512, qkvb + 1024, vmean, 1.f / 1024.f);
  // attn_row = v_mean @ out_w^T + out_b
  matvec512<<<512, 256, 0, stream>>>(vmean, outw, outb, arow, 1.f);
  add_ln2<<<4096, 256, 0, stream>>>(x, arow, ln2w, ln2b, x2, xl2);
  cvt_bf16<<<1024, 256, 0, stream>>>(fc1w, w1b, 2048 * 512);
  cvt_bf16<<<1024, 256, 0, stream>>>(fc2w, w2b, 512 * 2048);
  // fc1 + gelu -> hact (bf16)
  gemm_bt<128, 0><<<dim3(32, 16), 256, 0, stream>>>(xl2, w1b, fc1b, nullptr, hact, 4096, 2048, 512);
  // fc2 + bias + residual -> d_out (f32)
  gemm_bt<64, 1><<<dim3(32, 8), 256, 0, stream>>>(hact, w2b, fc2b, x2, d_out, 4096, 512, 2048);
}

// Round 2
// 98.867 us; speedup vs baseline: 1.0315x; 1.0315x over previous
//
#include <hip/hip_runtime.h>
#include <hip/hip_bf16.h>
#include <math.h>

#define EPSLN 1e-5f

typedef __attribute__((ext_vector_type(8))) short short8;
typedef __attribute__((ext_vector_type(4))) float f32x4;
typedef __attribute__((ext_vector_type(4))) unsigned short u16x4;

__device__ inline unsigned short f2bf(float f){
  unsigned int u = __float_as_uint(f);
  u += 0x7fffu + ((u >> 16) & 1u);
  return (unsigned short)(u >> 16);
}

__device__ inline float wred(float v){
  #pragma unroll
  for(int o = 32; o > 0; o >>= 1) v += __shfl_down(v, o, 64);
  return v;
}

// butterfly: all 64 lanes end with the total
__device__ inline float wredb(float v){
  #pragma unroll
  for(int o = 1; o < 64; o <<= 1) v += __shfl_xor(v, o, 64);
  return v;
}

// ---------------------------------------------------------------------------
// K1: per-batch column sum of LN1(x). Wave-per-row, no barriers.
// grid 64 blocks (4 batches x 16), 4 waves/block, 16 rows/wave.
// ---------------------------------------------------------------------------
__global__ __launch_bounds__(256) void ln1_colsum(
    const float* __restrict__ x, const float* __restrict__ w,
    const float* __restrict__ bb, float* __restrict__ colsum)
{
  const int tid = threadIdx.x, lane = tid & 63, wv = tid >> 6;
  const int b = blockIdx.x >> 4;
  const int rbase = ((blockIdx.x & 15) << 6) + (wv << 4);
  const f32x4* wp = (const f32x4*)w;
  const f32x4* bp = (const f32x4*)bb;
  f32x4 w1 = wp[lane * 2], w2 = wp[lane * 2 + 1];
  f32x4 b1 = bp[lane * 2], b2 = bp[lane * 2 + 1];
  f32x4 a1 = (f32x4)(0.f), a2 = (f32x4)(0.f);
  for(int i = 0; i < 16; i++){
    const size_t row = (size_t)(b << 10) + rbase + i;
    const f32x4* xr = (const f32x4*)(x + row * 512);
    f32x4 v1 = xr[lane * 2], v2 = xr[lane * 2 + 1];
    float s = v1[0]+v1[1]+v1[2]+v1[3] + v2[0]+v2[1]+v2[2]+v2[3];
    float q = v1[0]*v1[0]+v1[1]*v1[1]+v1[2]*v1[2]+v1[3]*v1[3]
            + v2[0]*v2[0]+v2[1]*v2[1]+v2[2]*v2[2]+v2[3]*v2[3];
    s = wredb(s); q = wredb(q);
    float mu = s * (1.f / 512.f);
    float rs = rsqrtf(q * (1.f / 512.f) - mu * mu + EPSLN);
    #pragma unroll
    for(int j = 0; j < 4; j++){
      a1[j] += (v1[j] - mu) * rs * w1[j] + b1[j];
      a2[j] += (v2[j] - mu) * rs * w2[j] + b2[j];
    }
  }
  float* cs = colsum + (b << 9) + lane * 8;
  #pragma unroll
  for(int j = 0; j < 4; j++){
    atomicAdd(cs + j,     a1[j]);
    atomicAdd(cs + 4 + j, a2[j]);
  }
}

// ---------------------------------------------------------------------------
// K2: out[b*512+n] = scale * dot(vec[b], W[n]) + bias[n]    (wave per output)
// ---------------------------------------------------------------------------
__global__ __launch_bounds__(256) void matvec512(
    const float* __restrict__ vec, const float* __restrict__ Wm,
    const float* __restrict__ bias, float* __restrict__ outv, float scale)
{
  int gw = blockIdx.x * 4 + (threadIdx.x >> 6);
  int lane = threadIdx.x & 63;
  int b = gw >> 9, n = gw & 511;
  const f32x4* vr = (const f32x4*)(vec + ((size_t)b << 9));
  const f32x4* wr = (const f32x4*)(Wm + ((size_t)n << 9));
  f32x4 v1 = vr[lane * 2], v2 = vr[lane * 2 + 1];
  f32x4 w1 = wr[lane * 2], w2 = wr[lane * 2 + 1];
  float s = 0.f;
  #pragma unroll
  for(int i = 0; i < 4; i++) s += v1[i] * w1[i] + v2[i] * w2[i];
  s = wred(s);
  if(lane == 0) outv[gw] = s * scale + bias[n];
}

// ---------------------------------------------------------------------------
// K3: xl2 = LN2(x + arow) as bf16. Wave-per-row, no barriers. grid 1024.
// ---------------------------------------------------------------------------
__global__ __launch_bounds__(256) void add_ln2(
    const float* __restrict__ x, const float* __restrict__ arow,
    const float* __restrict__ w, const float* __restrict__ bb,
    unsigned short* __restrict__ xl2)
{
  const int tid = threadIdx.x, lane = tid & 63, wv = tid >> 6;
  const size_t row = (size_t)blockIdx.x * 4 + wv;
  const int b = (int)(row >> 10);
  const f32x4* xr = (const f32x4*)(x + row * 512);
  const f32x4* ar = (const f32x4*)(arow + ((size_t)b << 9));
  f32x4 v1 = xr[lane * 2], v2 = xr[lane * 2 + 1];
  f32x4 r1 = ar[lane * 2], r2 = ar[lane * 2 + 1];
  #pragma unroll
  for(int j = 0; j < 4; j++){ v1[j] += r1[j]; v2[j] += r2[j]; }
  float s = v1[0]+v1[1]+v1[2]+v1[3] + v2[0]+v2[1]+v2[2]+v2[3];
  float q = v1[0]*v1[0]+v1[1]*v1[1]+v1[2]*v1[2]+v1[3]*v1[3]
          + v2[0]*v2[0]+v2[1]*v2[1]+v2[2]*v2[2]+v2[3]*v2[3];
  s = wredb(s); q = wredb(q);
  float mu = s * (1.f / 512.f);
  float rs = rsqrtf(q * (1.f / 512.f) - mu * mu + EPSLN);
  const f32x4* wp = (const f32x4*)w;
  const f32x4* bp = (const f32x4*)bb;
  f32x4 w1 = wp[lane * 2], w2 = wp[lane * 2 + 1];
  f32x4 b1 = bp[lane * 2], b2 = bp[lane * 2 + 1];
  u16x4 o1, o2;
  #pragma unroll
  for(int j = 0; j < 4; j++){
    o1[j] = f2bf((v1[j] - mu) * rs * w1[j] + b1[j]);
    o2[j] = f2bf((v2[j] - mu) * rs * w2[j] + b2[j]);
  }
  u16x4* op = (u16x4*)(xl2 + row * 512 + lane * 8);
  op[0] = o1; op[1] = o2;
}

// ---------------------------------------------------------------------------
// K4: fused f32 -> bf16 conversion of both weight matrices (1M elems each)
// ---------------------------------------------------------------------------
__global__ __launch_bounds__(256) void cvt2_bf16(
    const float* __restrict__ inA, const float* __restrict__ inB,
    unsigned short* __restrict__ oA, unsigned short* __restrict__ oB)
{
  int i = (blockIdx.x * 256 + threadIdx.x) * 4;
  const float* src; unsigned short* dst; int off;
  if(i < (1 << 20)){ src = inA; dst = oA; off = i; }
  else             { src = inB; dst = oB; off = i - (1 << 20); }
  f32x4 v = *(const f32x4*)(src + off);
  u16x4 r;
  #pragma unroll
  for(int j = 0; j < 4; j++) r[j] = f2bf(v[j]);
  *(u16x4*)(dst + off) = r;
}

// ---------------------------------------------------------------------------
// K5: bf16 MFMA GEMM, 2-phase double-buffered (T3-min structure).
// out[m,n] = sum_k A[m,k]*W[n,k] + bias[n] (+ epilogue)
// 4 waves 2x2, wave computes 64 x BN/2. BK=32.
// EPI==0: gelu -> bf16 out ; EPI==1: + x + arow -> f32 out
// ---------------------------------------------------------------------------
__device__ inline void gld_lds16(const void* g, void* l){
  __builtin_amdgcn_global_load_lds(
      (const __attribute__((address_space(1))) void*)g,
      (__attribute__((address_space(3))) void*)l, 16, 0, 0);
}

template<int BM, int BN, int EPI>
__global__ __launch_bounds__(256) void gemm_bt(
    const unsigned short* __restrict__ A, const unsigned short* __restrict__ W,
    const float* __restrict__ bias, const float* __restrict__ resx,
    const float* __restrict__ resrow, void* __restrict__ outp,
    int M, int N, int K)
{
  constexpr int BK = 32, NI = BN / 32;
  __shared__ __align__(16) unsigned short sA[2][BM * BK];
  __shared__ __align__(16) unsigned short sB[2][BN * BK];
  const int tid = threadIdx.x, lane = tid & 63, wv = tid >> 6;
  const int wm = wv >> 1, wn = wv & 1;
  const int m0 = blockIdx.x * BM, n0 = blockIdx.y * BN;

  f32x4 acc[4][NI];
  #pragma unroll
  for(int i = 0; i < 4; i++)
    #pragma unroll
    for(int j = 0; j < NI; j++) acc[i][j] = (f32x4)(0.f);

  const int rowS = tid >> 2;         // 0..63
  const int colb = (tid & 3) * 16;   // byte within 64B K-row

  auto stage = [&](int buf, int k0){
    #pragma unroll
    for(int p = 0; p < BM / 64; p++){
      const char* g = (const char*)(A + (size_t)(m0 + rowS + p * 64) * K + k0) + colb;
      gld_lds16(g, (char*)sA[buf] + p * 4096 + wv * 1024);
    }
    #pragma unroll
    for(int p = 0; p < BN / 64; p++){
      const char* g = (const char*)(W + (size_t)(n0 + rowS + p * 64) * K + k0) + colb;
      gld_lds16(g, (char*)sB[buf] + p * 4096 + wv * 1024);
    }
  };

  const int NT = K / BK;
  stage(0, 0);
  __syncthreads();
  int cur = 0;
  for(int t = 0; t < NT; ++t){
    if(t + 1 < NT) stage(cur ^ 1, (t + 1) * BK);   // loads fly during MFMA
    short8 af[4], bf[NI];
    const int kof = (lane >> 4) * 8;
    #pragma unroll
    for(int mi = 0; mi < 4; mi++)
      af[mi] = *(const short8*)(sA[cur] + (wm * 64 + mi * 16 + (lane & 15)) * BK + kof);
    #pragma unroll
    for(int ni = 0; ni < NI; ni++)
      bf[ni] = *(const short8*)(sB[cur] + (wn * (BN / 2) + ni * 16 + (lane & 15)) * BK + kof);
    #pragma unroll
    for(int mi = 0; mi < 4; mi++)
      #pragma unroll
      for(int ni = 0; ni < NI; ni++)
        acc[mi][ni] = __builtin_amdgcn_mfma_f32_16x16x32_bf16(af[mi], bf[ni], acc[mi][ni], 0, 0, 0);
    __syncthreads();   // drains vm (staged tile ready) + lgkm (reads done)
    cur ^= 1;
  }

  const int r0 = m0 + wm * 64 + (lane >> 4) * 4;
  const int c0 = n0 + wn * (BN / 2) + (lane & 15);
  #pragma unroll
  for(int mi = 0; mi < 4; mi++)
    #pragma unroll
    for(int ni = 0; ni < NI; ni++){
      int cc = c0 + ni * 16;
      float bi = bias[cc];
      #pragma unroll
      for(int j = 0; j < 4; j++){
        int rr = r0 + mi * 16 + j;
        float v = acc[mi][ni][j] + bi;
        if constexpr(EPI == 0){
          float gl = 0.5f * v * (1.0f + erff(v * 0.70710678118f));
          ((unsigned short*)outp)[(size_t)rr * N + cc] = f2bf(gl);
        } else {
          v += resx[(size_t)rr * N + cc] + resrow[((rr >> 10) << 9) + cc];
          ((float*)outp)[(size_t)rr * N + cc] = v;
        }
      }
    }
}

// ---------------------------------------------------------------------------
extern "C" void kernel_launch(void* const* d_in, const int* in_sizes, int n_in,
                              void* d_out, int out_size, void* d_ws, size_t ws_size,
                              hipStream_t stream)
{
  (void)in_sizes; (void)n_in; (void)out_size; (void)ws_size;
  const float* x    = (const float*)d_in[0];
  const float* ln1w = (const float*)d_in[1];
  const float* ln1b = (const float*)d_in[2];
  const float* qkvw = (const float*)d_in[3];
  const float* qkvb = (const float*)d_in[4];
  const float* outw = (const float*)d_in[5];
  const float* outb = (const float*)d_in[6];
  const float* ln2w = (const float*)d_in[7];
  const float* ln2b = (const float*)d_in[8];
  const float* fc1w = (const float*)d_in[9];
  const float* fc1b = (const float*)d_in[10];
  const float* fc2w = (const float*)d_in[11];
  const float* fc2b = (const float*)d_in[12];

  char* ws = (char*)d_ws;
  float*          colsum = (float*)ws;                       // 8 KB
  float*          vmean  = (float*)(ws + 8192);              // 8 KB
  float*          arow   = (float*)(ws + 16384);             // 8 KB
  unsigned short* xl2    = (unsigned short*)(ws + 32768);                      // 4 MB
  unsigned short* w1b    = (unsigned short*)(ws + 32768 + 4194304);            // 2 MB
  unsigned short* w2b    = (unsigned short*)(ws + 32768 + 4194304 + 2097152);  // 2 MB
  unsigned short* hact   = (unsigned short*)(ws + 32768 + 4194304 + 2097152 + 2097152); // 16 MB

  hipMemsetAsync(colsum, 0, 2048 * 4, stream);
  ln1_colsum<<<64, 256, 0, stream>>>(x, ln1w, ln1b, colsum);
  // v_mean = (colsum/S) @ Wv^T + bv   (Wv = qkv_w rows [1024,1536))
  matvec512<<<512, 256, 0, stream>>>(colsum, qkvw + 2 * 512 * 512, qkvb + 1024, vmean, 1.f / 1024.f);
  // attn_row = v_mean @ out_w^T + out_b
  matvec512<<<512, 256, 0, stream>>>(vmean, outw, outb, arow, 1.f);
  add_ln2<<<1024, 256, 0, stream>>>(x, arow, ln2w, ln2b, xl2);
  cvt2_bf16<<<2048, 256, 0, stream>>>(fc1w, fc2w, w1b, w2b);
  // fc1 + gelu -> hact (bf16)
  gemm_bt<128, 128, 0><<<dim3(32, 16), 256, 0, stream>>>(
      xl2, w1b, fc1b, nullptr, nullptr, hact, 4096, 2048, 512);
  // fc2 + bias + x + arow -> d_out (f32)
  gemm_bt<128, 64, 1><<<dim3(32, 8), 256, 0, stream>>>(
      hact, w2b, fc2b, x, arow, d_out, 4096, 512, 2048);
}